// Round 7
// baseline (254.458 us; speedup 1.0000x reference)
//
#include <hip/hip_runtime.h>
#include <hip/hip_bf16.h>

// HyConv round 7: XCD-local (8-copy) bucket build + bf16 intermediates + reg-blocked gemm.
// memset(ctr) -> build_gemm (role=bi%3: 1 gemm : 2 build) -> phase1_pull -> phase2_pull
// Round-6 lesson: 8-XCD shared dirty lines caused ~6x re-writeback of src arrays (79MB).
// Copies are balanced by construction (bi&7 stratified across bi%3!=0), so correctness
// never depends on the real block->XCD mapping; only locality does.

#define BB 4
#define NN 10000
#define MM 10000
#define EE 160000
#define CC 128
#define BM (BB * MM)   // 40000 hyperedge buckets
#define BN (BB * NN)   // 40000 node buckets
#define NCOPY 8
#define CAPX 24        // per-copy bucket capacity; per-copy deg ~ Poisson(2), P[>=24]~1e-15

typedef unsigned short u16;
using bf16 = __hip_bfloat16;
using bf162 = __hip_bfloat162;

// ---------------- fused: gemm (bi%3==0) || build (bi%3!=0) ----------------
// grid = 3750: 1250 gemm blocks (32 rows each), 2500 build blocks (640k edges).
__global__ __launch_bounds__(256) void build_gemm_k(const int* __restrict__ H,
                                                    int* __restrict__ ctr,
                                                    u16* __restrict__ srcA,
                                                    u16* __restrict__ srcB,
                                                    const float* __restrict__ x,
                                                    const float* __restrict__ theta,
                                                    bf16* __restrict__ xt) {
    __shared__ float sTh[64 * 128];  // 32 KB
    __shared__ float sX[32 * 128];   // 16 KB
    const int bi = blockIdx.x;

    if (bi % 3 != 0) {
        // ---- build: one thread per edge, XCD-local copy = bi & 7 ----
        const int j = bi - bi / 3 - 1;               // 0..2499 among build blocks
        const int g = j * 256 + threadIdx.x;         // 0..639,999
        if (g >= BB * EE) return;
        const int cp = bi & 7;
        const int b = g / EE, e = g - b * EE;
        const int nd = H[b * 2 * EE + e];
        const int he = H[b * 2 * EE + EE + e];
        const int bktA = b * MM + he;
        const int s = atomicAdd(&ctr[cp * (BM + BN) + bktA], 1);
        if (s < CAPX) srcA[((size_t)cp * BM + bktA) * CAPX + s] = (u16)nd;
        const int bktB = b * NN + nd;
        const int q = atomicAdd(&ctr[cp * (BM + BN) + BM + bktB], 1);
        if (q < CAPX) srcB[((size_t)cp * BN + bktB) * CAPX + q] = (u16)he;
        return;
    }

    // ---- gemm: 32 rows x 128 cols per block; thread = 8 rows x 2 cols ----
    const int tid = threadIdx.x;
    const int row0 = (bi / 3) * 32;  // 0..1249 -> rows 0..39968
    {
        const float4* src = (const float4*)&x[row0 * 128];  // 1024 float4
        float4* dst = (float4*)sX;
#pragma unroll
        for (int i = 0; i < 4; ++i) dst[tid + 256 * i] = src[tid + 256 * i];
    }
    const int cg2 = (tid & 63) * 2;  // column pair base (0..126)
    const int rg = tid >> 6;         // row group 0..3 (rows rg*8 .. rg*8+7)
    float ax[8], ay[8];
#pragma unroll
    for (int r = 0; r < 8; ++r) { ax[r] = 0.f; ay[r] = 0.f; }

    for (int half = 0; half < 2; ++half) {
        __syncthreads();
        {
            const float4* src = (const float4*)&theta[half * 64 * 128];
            float4* dst = (float4*)sTh;
#pragma unroll
            for (int i = 0; i < 8; ++i) dst[tid + 256 * i] = src[tid + 256 * i];
        }
        __syncthreads();
#pragma unroll
        for (int k4 = 0; k4 < 16; ++k4) {
            const int kk = 4 * k4;
            const float2 t0 = *(const float2*)&sTh[(kk + 0) * 128 + cg2];
            const float2 t1 = *(const float2*)&sTh[(kk + 1) * 128 + cg2];
            const float2 t2 = *(const float2*)&sTh[(kk + 2) * 128 + cg2];
            const float2 t3 = *(const float2*)&sTh[(kk + 3) * 128 + cg2];
#pragma unroll
            for (int r = 0; r < 8; ++r) {
                // all lanes of a wave share rg -> broadcast LDS read (conflict-free)
                const float4 xv =
                    *(const float4*)&sX[(rg * 8 + r) * 128 + half * 64 + kk];
                ax[r] = fmaf(xv.x, t0.x, ax[r]); ay[r] = fmaf(xv.x, t0.y, ay[r]);
                ax[r] = fmaf(xv.y, t1.x, ax[r]); ay[r] = fmaf(xv.y, t1.y, ay[r]);
                ax[r] = fmaf(xv.z, t2.x, ax[r]); ay[r] = fmaf(xv.z, t2.y, ay[r]);
                ax[r] = fmaf(xv.w, t3.x, ax[r]); ay[r] = fmaf(xv.w, t3.y, ay[r]);
            }
        }
    }
#pragma unroll
    for (int r = 0; r < 8; ++r) {
        bf162 h;
        h.x = __float2bfloat16(ax[r]);
        h.y = __float2bfloat16(ay[r]);
        *(bf162*)&xt[(size_t)(row0 + rg * 8 + r) * 128 + cg2] = h;
    }
}

// ---------------- gather helper: accumulate one bf16 row (2 channels/lane) ----------
__device__ __forceinline__ void gacc(const bf16* __restrict__ base, int idx, int lane,
                                     float& sx, float& sy) {
    const unsigned raw = *(const unsigned*)(base + (size_t)idx * CC + lane * 2);
    sx += __uint_as_float(raw << 16);
    sy += __uint_as_float(raw & 0xffff0000u);
}

// ---------------- phase1: x_edge[bkt] = mean over incident nodes of xt ----------------
__global__ __launch_bounds__(256) void phase1_pull(const bf16* __restrict__ xt,
                                                   const int* __restrict__ ctr,
                                                   const u16* __restrict__ srcA,
                                                   bf16* __restrict__ x_edge) {
    const int wid = (blockIdx.x * 256 + threadIdx.x) >> 6;  // bucket = b*MM+he
    const int lane = threadIdx.x & 63;
    const bf16* base = xt + (size_t)(wid / MM) * NN * CC;
    float sx = 0.f, sy = 0.f;
    int total = 0;
#pragma unroll
    for (int cp = 0; cp < NCOPY; ++cp) {
        int cnt = ctr[cp * (BM + BN) + wid];
        cnt = cnt > CAPX ? CAPX : cnt;
        const u16* lst = srcA + ((size_t)cp * BM + wid) * CAPX;
        int i = 0;
        for (; i + 4 <= cnt; i += 4) {
            const uint2 pk = *(const uint2*)&lst[i];
            gacc(base, pk.x & 0xffff, lane, sx, sy);
            gacc(base, pk.x >> 16, lane, sx, sy);
            gacc(base, pk.y & 0xffff, lane, sx, sy);
            gacc(base, pk.y >> 16, lane, sx, sy);
        }
        for (; i < cnt; ++i) gacc(base, lst[i], lane, sx, sy);
        total += cnt;
    }
    const float w = total ? 1.0f / (float)total : 0.f;
    bf162 h;
    h.x = __float2bfloat16(sx * w);
    h.y = __float2bfloat16(sy * w);
    *(bf162*)&x_edge[(size_t)wid * CC + lane * 2] = h;
}

// ---------------- phase2: out[bkt] = mean over incident hyperedges + bias ------------
__global__ __launch_bounds__(256) void phase2_pull(const bf16* __restrict__ x_edge,
                                                   const int* __restrict__ ctr,
                                                   const u16* __restrict__ srcB,
                                                   const float* __restrict__ bias,
                                                   float* __restrict__ out) {
    const int wid = (blockIdx.x * 256 + threadIdx.x) >> 6;  // bucket = b*NN+nd
    const int lane = threadIdx.x & 63;
    const bf16* base = x_edge + (size_t)(wid / NN) * MM * CC;
    float sx = 0.f, sy = 0.f;
    int total = 0;
#pragma unroll
    for (int cp = 0; cp < NCOPY; ++cp) {
        int cnt = ctr[cp * (BM + BN) + BM + wid];
        cnt = cnt > CAPX ? CAPX : cnt;
        const u16* lst = srcB + ((size_t)cp * BN + wid) * CAPX;
        int i = 0;
        for (; i + 4 <= cnt; i += 4) {
            const uint2 pk = *(const uint2*)&lst[i];
            gacc(base, pk.x & 0xffff, lane, sx, sy);
            gacc(base, pk.x >> 16, lane, sx, sy);
            gacc(base, pk.y & 0xffff, lane, sx, sy);
            gacc(base, pk.y >> 16, lane, sx, sy);
        }
        for (; i < cnt; ++i) gacc(base, lst[i], lane, sx, sy);
        total += cnt;
    }
    const float w = total ? 1.0f / (float)total : 0.f;
    const float2 bv = *(const float2*)&bias[lane * 2];
    float2 o;
    o.x = sx * w + bv.x;
    o.y = sy * w + bv.y;
    *(float2*)&out[(size_t)wid * CC + lane * 2] = o;
}

extern "C" void kernel_launch(void* const* d_in, const int* in_sizes, int n_in,
                              void* d_out, int out_size, void* d_ws, size_t ws_size,
                              hipStream_t stream) {
    const float* x = (const float*)d_in[0];
    const int* H = (const int*)d_in[1];
    const float* theta = (const float*)d_in[2];
    const float* bias = (const float*)d_in[3];
    float* out = (float*)d_out;

    // workspace (53.8 MB): xt(bf16) | x_edge(bf16) | ctr(8 copies) | srcA | srcB
    bf16* xt = (bf16*)d_ws;                                   // 40000*128 bf16 = 10.24 MB
    bf16* x_edge = xt + (size_t)BB * NN * CC;                 // 10.24 MB
    int* ctr = (int*)(x_edge + (size_t)BB * MM * CC);         // 8*80000 ints = 2.56 MB
    u16* srcA = (u16*)(ctr + NCOPY * (BM + BN));              // 8*40000*24 u16 = 15.36 MB
    u16* srcB = srcA + (size_t)NCOPY * BM * CAPX;             // 15.36 MB

    hipMemsetAsync(ctr, 0, (size_t)NCOPY * (BM + BN) * sizeof(int), stream);

    build_gemm_k<<<3750, 256, 0, stream>>>(H, ctr, srcA, srcB, x, theta, xt);
    phase1_pull<<<BM / 4, 256, 0, stream>>>(xt, ctr, srcA, x_edge);
    phase2_pull<<<BN / 4, 256, 0, stream>>>(x_edge, ctr, srcB, bias, out);
}

// Round 8
// 197.400 us; speedup vs baseline: 1.2890x; 1.2890x over previous
//
#include <hip/hip_runtime.h>
#include <hip/hip_bf16.h>

// HyConv round 8: XCD-local 8-copy build (kept, CAPX 24->16) + in-wave LDS merge in
// the phase kernels (lanes 0-7 parallel-load copy counts, shuffle prefix, copy to LDS,
// then flat 8-wide uint4 gather — fixes round 7's fragmented-gather regression).
// memset(ctr) -> build_gemm (1 gemm : 2 build) -> phase1_pull -> phase2_pull

#define BB 4
#define NN 10000
#define MM 10000
#define EE 160000
#define CC 128
#define BM (BB * MM)   // 40000 hyperedge buckets
#define BN (BB * NN)   // 40000 node buckets
#define NCOPY 8
#define CAPX 16        // per-copy bucket capacity; per-copy deg ~ Poisson(2), P[>=17]~5e-11

typedef unsigned short u16;
using bf16 = __hip_bfloat16;
using bf162 = __hip_bfloat162;

// ---------------- fused: gemm (bi%3==0) || build (bi%3!=0) ----------------
// grid = 3750: 1250 gemm blocks (32 rows each), 2500 build blocks (640k edges).
__global__ __launch_bounds__(256) void build_gemm_k(const int* __restrict__ H,
                                                    int* __restrict__ ctr,
                                                    u16* __restrict__ srcA,
                                                    u16* __restrict__ srcB,
                                                    const float* __restrict__ x,
                                                    const float* __restrict__ theta,
                                                    bf16* __restrict__ xt) {
    __shared__ float sTh[64 * 128];  // 32 KB
    __shared__ float sX[32 * 128];   // 16 KB
    const int bi = blockIdx.x;

    if (bi % 3 != 0) {
        // ---- build: one thread per edge, XCD-local copy = bi & 7 ----
        const int j = bi - bi / 3 - 1;               // 0..2499 among build blocks
        const int g = j * 256 + threadIdx.x;         // 0..639,999
        if (g >= BB * EE) return;
        const int cp = bi & 7;
        const int b = g / EE, e = g - b * EE;
        const int nd = H[b * 2 * EE + e];
        const int he = H[b * 2 * EE + EE + e];
        const int bktA = b * MM + he;
        const int s = atomicAdd(&ctr[cp * (BM + BN) + bktA], 1);
        if (s < CAPX) srcA[((size_t)cp * BM + bktA) * CAPX + s] = (u16)nd;
        const int bktB = b * NN + nd;
        const int q = atomicAdd(&ctr[cp * (BM + BN) + BM + bktB], 1);
        if (q < CAPX) srcB[((size_t)cp * BN + bktB) * CAPX + q] = (u16)he;
        return;
    }

    // ---- gemm: 32 rows x 128 cols per block; thread = 8 rows x 2 cols ----
    const int tid = threadIdx.x;
    const int row0 = (bi / 3) * 32;  // 0..1249 -> rows 0..39968
    {
        const float4* src = (const float4*)&x[row0 * 128];  // 1024 float4
        float4* dst = (float4*)sX;
#pragma unroll
        for (int i = 0; i < 4; ++i) dst[tid + 256 * i] = src[tid + 256 * i];
    }
    const int cg2 = (tid & 63) * 2;  // column pair base (0..126)
    const int rg = tid >> 6;         // row group 0..3
    float ax[8], ay[8];
#pragma unroll
    for (int r = 0; r < 8; ++r) { ax[r] = 0.f; ay[r] = 0.f; }

    for (int half = 0; half < 2; ++half) {
        __syncthreads();
        {
            const float4* src = (const float4*)&theta[half * 64 * 128];
            float4* dst = (float4*)sTh;
#pragma unroll
            for (int i = 0; i < 8; ++i) dst[tid + 256 * i] = src[tid + 256 * i];
        }
        __syncthreads();
#pragma unroll
        for (int k4 = 0; k4 < 16; ++k4) {
            const int kk = 4 * k4;
            const float2 t0 = *(const float2*)&sTh[(kk + 0) * 128 + cg2];
            const float2 t1 = *(const float2*)&sTh[(kk + 1) * 128 + cg2];
            const float2 t2 = *(const float2*)&sTh[(kk + 2) * 128 + cg2];
            const float2 t3 = *(const float2*)&sTh[(kk + 3) * 128 + cg2];
#pragma unroll
            for (int r = 0; r < 8; ++r) {
                const float4 xv =
                    *(const float4*)&sX[(rg * 8 + r) * 128 + half * 64 + kk];
                ax[r] = fmaf(xv.x, t0.x, ax[r]); ay[r] = fmaf(xv.x, t0.y, ay[r]);
                ax[r] = fmaf(xv.y, t1.x, ax[r]); ay[r] = fmaf(xv.y, t1.y, ay[r]);
                ax[r] = fmaf(xv.z, t2.x, ax[r]); ay[r] = fmaf(xv.z, t2.y, ay[r]);
                ax[r] = fmaf(xv.w, t3.x, ax[r]); ay[r] = fmaf(xv.w, t3.y, ay[r]);
            }
        }
    }
#pragma unroll
    for (int r = 0; r < 8; ++r) {
        bf162 h;
        h.x = __float2bfloat16(ax[r]);
        h.y = __float2bfloat16(ay[r]);
        *(bf162*)&xt[(size_t)(row0 + rg * 8 + r) * 128 + cg2] = h;
    }
}

// ---------------- gather helper: accumulate one bf16 row (2 channels/lane) ----------
__device__ __forceinline__ void gacc(const bf16* __restrict__ base, int idx, int lane,
                                     float& sx, float& sy) {
    const unsigned raw = *(const unsigned*)(base + (size_t)idx * CC + lane * 2);
    sx += __uint_as_float(raw << 16);
    sy += __uint_as_float(raw & 0xffff0000u);
}

// ---------------- in-wave merge of 8 copy-lists into LDS, then flat gather ----------
// side_off: 0 for A-side counters, BM for B-side. Bx: BM or BN (copy stride).
// Returns total entry count; flat list left in buf[0..total).
__device__ __forceinline__ int merge_lists(const int* __restrict__ ctr,
                                           const u16* __restrict__ src,
                                           int side_off, int Bx, int wid, int lane,
                                           u16* __restrict__ buf) {
    int cnt = 0;
    if (lane < NCOPY) {
        cnt = ctr[lane * (BM + BN) + side_off + wid];
        cnt = cnt > CAPX ? CAPX : cnt;
    }
    int pre = cnt;  // inclusive prefix over lanes 0..7 (higher lanes: garbage, unused)
#pragma unroll
    for (int d = 1; d < 8; d <<= 1) {
        int o = __shfl_up(pre, d, 64);
        if (lane >= d) pre += o;
    }
    const int base = pre - cnt;
    int total = __shfl(pre, 7, 64);
    total = total > 64 ? 64 : total;
    if (lane < NCOPY && cnt) {
        const u16* lst = src + ((size_t)lane * Bx + wid) * CAPX;
        for (int j = 0; j < cnt; ++j) {
            const int p = base + j;
            if (p < 64) buf[p] = lst[j];
        }
    }
    __syncthreads();  // publish LDS lists (block-wide; all waves reach it)
    return total;
}

// ---------------- phase1: x_edge[bkt] = mean over incident nodes of xt ----------------
__global__ __launch_bounds__(256) void phase1_pull(const bf16* __restrict__ xt,
                                                   const int* __restrict__ ctr,
                                                   const u16* __restrict__ srcA,
                                                   bf16* __restrict__ x_edge) {
    __shared__ __align__(16) u16 buf[4 * 64];  // 4 waves x 64 entries
    const int wid = (blockIdx.x * 256 + threadIdx.x) >> 6;  // bucket = b*MM+he
    const int lane = threadIdx.x & 63;
    u16* wbuf = &buf[(threadIdx.x >> 6) * 64];
    const int total = merge_lists(ctr, srcA, 0, BM, wid, lane, wbuf);

    const bf16* base = xt + (size_t)(wid / MM) * NN * CC;
    float sx = 0.f, sy = 0.f;
    int i = 0;
    for (; i + 8 <= total; i += 8) {
        const uint4 pk = *(const uint4*)&wbuf[i];  // LDS broadcast read
        gacc(base, pk.x & 0xffff, lane, sx, sy);
        gacc(base, pk.x >> 16, lane, sx, sy);
        gacc(base, pk.y & 0xffff, lane, sx, sy);
        gacc(base, pk.y >> 16, lane, sx, sy);
        gacc(base, pk.z & 0xffff, lane, sx, sy);
        gacc(base, pk.z >> 16, lane, sx, sy);
        gacc(base, pk.w & 0xffff, lane, sx, sy);
        gacc(base, pk.w >> 16, lane, sx, sy);
    }
    for (; i < total; ++i) gacc(base, wbuf[i], lane, sx, sy);
    const float w = total ? 1.0f / (float)total : 0.f;
    bf162 h;
    h.x = __float2bfloat16(sx * w);
    h.y = __float2bfloat16(sy * w);
    *(bf162*)&x_edge[(size_t)wid * CC + lane * 2] = h;
}

// ---------------- phase2: out[bkt] = mean over incident hyperedges + bias ------------
__global__ __launch_bounds__(256) void phase2_pull(const bf16* __restrict__ x_edge,
                                                   const int* __restrict__ ctr,
                                                   const u16* __restrict__ srcB,
                                                   const float* __restrict__ bias,
                                                   float* __restrict__ out) {
    __shared__ __align__(16) u16 buf[4 * 64];
    const int wid = (blockIdx.x * 256 + threadIdx.x) >> 6;  // bucket = b*NN+nd
    const int lane = threadIdx.x & 63;
    u16* wbuf = &buf[(threadIdx.x >> 6) * 64];
    const int total = merge_lists(ctr, srcB, BM, BN, wid, lane, wbuf);

    const bf16* base = x_edge + (size_t)(wid / NN) * MM * CC;
    float sx = 0.f, sy = 0.f;
    int i = 0;
    for (; i + 8 <= total; i += 8) {
        const uint4 pk = *(const uint4*)&wbuf[i];
        gacc(base, pk.x & 0xffff, lane, sx, sy);
        gacc(base, pk.x >> 16, lane, sx, sy);
        gacc(base, pk.y & 0xffff, lane, sx, sy);
        gacc(base, pk.y >> 16, lane, sx, sy);
        gacc(base, pk.z & 0xffff, lane, sx, sy);
        gacc(base, pk.z >> 16, lane, sx, sy);
        gacc(base, pk.w & 0xffff, lane, sx, sy);
        gacc(base, pk.w >> 16, lane, sx, sy);
    }
    for (; i < total; ++i) gacc(base, wbuf[i], lane, sx, sy);
    const float w = total ? 1.0f / (float)total : 0.f;
    const float2 bv = *(const float2*)&bias[lane * 2];
    float2 o;
    o.x = sx * w + bv.x;
    o.y = sy * w + bv.y;
    *(float2*)&out[(size_t)wid * CC + lane * 2] = o;
}

extern "C" void kernel_launch(void* const* d_in, const int* in_sizes, int n_in,
                              void* d_out, int out_size, void* d_ws, size_t ws_size,
                              hipStream_t stream) {
    const float* x = (const float*)d_in[0];
    const int* H = (const int*)d_in[1];
    const float* theta = (const float*)d_in[2];
    const float* bias = (const float*)d_in[3];
    float* out = (float*)d_out;

    // workspace (~43.5 MB): xt(bf16) | x_edge(bf16) | ctr(8 copies) | srcA | srcB
    bf16* xt = (bf16*)d_ws;                                   // 10.24 MB
    bf16* x_edge = xt + (size_t)BB * NN * CC;                 // 10.24 MB
    int* ctr = (int*)(x_edge + (size_t)BB * MM * CC);         // 2.56 MB
    u16* srcA = (u16*)(ctr + NCOPY * (BM + BN));              // 10.24 MB
    u16* srcB = srcA + (size_t)NCOPY * BM * CAPX;             // 10.24 MB

    hipMemsetAsync(ctr, 0, (size_t)NCOPY * (BM + BN) * sizeof(int), stream);

    build_gemm_k<<<3750, 256, 0, stream>>>(H, ctr, srcA, srcB, x, theta, xt);
    phase1_pull<<<BM / 4, 256, 0, stream>>>(xt, ctr, srcA, x_edge);
    phase2_pull<<<BN / 4, 256, 0, stream>>>(x_edge, ctr, srcB, bias, out);
}